// Round 4
// baseline (139.801 us; speedup 1.0000x reference)
//
#include <hip/hip_runtime.h>

#define HW 16384

typedef __attribute__((ext_vector_type(8))) __bf16 bf16x8;
typedef __attribute__((ext_vector_type(4))) float floatx4;
typedef __attribute__((ext_vector_type(8))) unsigned short ushort8_t;

typedef const __attribute__((address_space(1))) unsigned int gu32;
typedef __attribute__((address_space(3))) unsigned int lu32;

__device__ __forceinline__ unsigned short f2bf(float f) {
    // round-to-nearest-even fp32 -> bf16
    unsigned int u = __builtin_bit_cast(unsigned int, f);
    unsigned int r = (u + 0x7FFFu + ((u >> 16) & 1u)) >> 16;
    return (unsigned short)r;
}

__device__ __forceinline__ void gload_lds16(const unsigned short* g, unsigned short* l) {
    __builtin_amdgcn_global_load_lds((gu32*)g, (lu32*)l, 16, 0, 0);
}

// Pre-convert W to bf16 in per-kt tiles [256 rows][64 k], XOR-swizzled so the main
// kernel can global_load_lds linearly and ds_read with the same involution.
// ushort index within tile: (row*64 + kl) ^ ((row&7)<<3); tile kt base = kt*16384.
__global__ void wconv_kernel(const float* __restrict__ w, unsigned short* __restrict__ wb) {
    int i = blockIdx.x * 256 + threadIdx.x;   // 65536 elements, i = row*256 + c
    int row = i >> 8, c = i & 255;
    int kt = c >> 6, kl = c & 63;
    int idx = (row * 64 + kl) ^ ((row & 7) << 3);
    wb[kt * 16384 + idx] = f2bf(w[i]);
}

// Block: 256 output channels x 64 pixels, K=256 in 4 steps of 64.
// 8 waves: nt = wv>>1 (16-px n-tile), mh = wv&1 (which two 16-row m-slices; all 4
// channel groups per wave so the lifting epilogue stays lane-local).
// W: LDS double-buffer via pre-swizzled global_load_lds (prefetch issued a full kt early).
// X: NO LDS — B-fragments built from 8 coalesced global dword loads + in-register bf16
// pack (lane l&15 = pixel, lane>>4 selects 8-channel chunk). Next-kt X loads issue at
// kt top so the pre-barrier vmcnt(0) drain finds them already landed.
__global__ __launch_bounds__(512, 4) void fused_gemm_lift(
        const float* __restrict__ x,
        const unsigned short* __restrict__ wb,
        const float* __restrict__ lp_v,
        const float* __restrict__ hp_v,
        const float* __restrict__ lp_h,
        const float* __restrict__ hp_h,
        float* __restrict__ out) {
    __shared__ alignas(16) unsigned short wbuf_s[2][16384];  // 2 x 32 KB W tiles

    const int tid  = threadIdx.x;
    const int wv   = tid >> 6;
    const int lane = tid & 63;
    const int nt   = wv >> 1;      // n-tile (16 px)
    const int mh   = wv & 1;       // m-slice half
    const int tile = blockIdx.x & 255;
    const int bb   = blockIdx.x >> 8;
    const int p0   = tile * 64;

    const int lrow = lane & 15;    // pixel within n-tile / row within m-slice
    const int kh   = lane >> 4;    // 8-elem k-chunk select
    const int fswz = (lrow & 7) << 3;

    const float* xb = x + (size_t)bb * 256 * HW;
    const float* xp = xb + p0 + nt * 16 + lrow;   // this lane's pixel column

    floatx4 acc[2][4];
    #pragma unroll
    for (int s = 0; s < 2; ++s)
        #pragma unroll
        for (int g = 0; g < 4; ++g) {
            floatx4 z = {0.f, 0.f, 0.f, 0.f};
            acc[s][g] = z;
        }

    float xf[2][16];

    // ---- prologue: W[0] -> wbuf[0], X[kt=0] -> regs ----
    #pragma unroll
    for (int pass = 0; pass < 4; ++pass) {
        int ch = pass * 512 + wv * 64;   // wave-uniform chunk base
        gload_lds16(wb + (size_t)(ch + lane) * 8, &wbuf_s[0][ch * 8]);
    }
    #pragma unroll
    for (int jj = 0; jj < 16; ++jj) {
        int ch = (jj >> 3) * 32 + kh * 8 + (jj & 7);
        xf[0][jj] = xp[(size_t)ch * HW];
    }
    __syncthreads();

    #pragma unroll
    for (int kt = 0; kt < 4; ++kt) {
        const int cw = kt & 1;

        // ---- issue next-tile loads first (land under this kt's compute) ----
        if (kt < 3) {
            #pragma unroll
            for (int pass = 0; pass < 4; ++pass) {
                int ch = pass * 512 + wv * 64;
                gload_lds16(wb + (size_t)(kt + 1) * 16384 + (size_t)(ch + lane) * 8,
                            &wbuf_s[cw ^ 1][ch * 8]);
            }
            #pragma unroll
            for (int jj = 0; jj < 16; ++jj) {
                int ch = (kt + 1) * 64 + (jj >> 3) * 32 + kh * 8 + (jj & 7);
                xf[cw ^ 1][jj] = xp[(size_t)ch * HW];
            }
        }

        // ---- compute: 2 kc x (pack B + 8 ds_read A + 8 MFMA) ----
        #pragma unroll
        for (int kc = 0; kc < 2; ++kc) {
            ushort8_t u;
            #pragma unroll
            for (int j = 0; j < 8; ++j) u[j] = f2bf(xf[cw][kc * 8 + j]);
            const bf16x8 bfv = __builtin_bit_cast(bf16x8, u);
            #pragma unroll
            for (int s = 0; s < 2; ++s) {
                bf16x8 af[4];
                #pragma unroll
                for (int g = 0; g < 4; ++g) {
                    int row = g * 64 + (mh * 2 + s) * 16 + lrow;
                    af[g] = *reinterpret_cast<const bf16x8*>(
                        &wbuf_s[cw][(row * 64 + kc * 32 + kh * 8) ^ fswz]);
                }
                #pragma unroll
                for (int g = 0; g < 4; ++g)
                    acc[s][g] = __builtin_amdgcn_mfma_f32_16x16x32_bf16(af[g], bfv, acc[s][g], 0, 0, 0);
            }
        }

        if (kt < 3) __syncthreads();
    }

    // ---- fused lifting epilogue (lane-local) ----
    // C/D map: col = lane&15 (pixel), row = 4*(lane>>4)+reg (channel)
    const int px = p0 + nt * 16 + lrow;
    const int h  = px >> 7;
    const int w  = px & 127;
    #pragma unroll
    for (int s = 0; s < 2; ++s)
        #pragma unroll
        for (int ri = 0; ri < 4; ++ri) {
            const int q = (mh * 2 + s) * 16 + kh * 4 + ri;   // 0..63
            const float lv0 = lp_v[2 * q], lv1 = lp_v[2 * q + 1];
            const float hv0 = hp_v[2 * q], hv1 = hp_v[2 * q + 1];
            const float lh0 = lp_h[2 * q], lh1 = lp_h[2 * q + 1];
            const float hh0 = hp_h[2 * q], hh1 = hp_h[2 * q + 1];
            float* outq = out + (size_t)(bb * 64 + q) * 65536;   // [256][256] plane
            const float a  = acc[s][0][ri];
            const float b2 = acc[s][1][ri];
            const float c2 = acc[s][2][ri];
            const float d2 = acc[s][3][ri];
            const float xl0 = lv0 * a + lv1 * b2;
            const float xl1 = hv0 * a + hv1 * b2;
            const float xh0 = lv0 * c2 + lv1 * d2;
            const float xh1 = hv0 * c2 + hv1 * d2;
            float2 r0 = make_float2(lh0 * xl0 + lh1 * xh0, hh0 * xl0 + hh1 * xh0);
            float2 r1 = make_float2(lh0 * xl1 + lh1 * xh1, hh0 * xl1 + hh1 * xh1);
            *reinterpret_cast<float2*>(outq + (size_t)(2 * h) * 256 + 2 * w)     = r0;
            *reinterpret_cast<float2*>(outq + (size_t)(2 * h + 1) * 256 + 2 * w) = r1;
        }
}

extern "C" void kernel_launch(void* const* d_in, const int* in_sizes, int n_in,
                              void* d_out, int out_size, void* d_ws, size_t ws_size,
                              hipStream_t stream) {
    const float* x   = (const float*)d_in[0];
    const float* w   = (const float*)d_in[1];
    const float* lpv = (const float*)d_in[2];
    const float* hpv = (const float*)d_in[3];
    const float* lph = (const float*)d_in[4];
    const float* hph = (const float*)d_in[5];
    float* outp = (float*)d_out;
    unsigned short* wbp = (unsigned short*)d_ws;   // 128 KB bf16 weights, pre-swizzled tiles

    wconv_kernel<<<dim3(256), dim3(256), 0, stream>>>(w, wbp);
    fused_gemm_lift<<<dim3(4096), dim3(512), 0, stream>>>(x, wbp, lpv, hpv, lph, hph, outp);
}

// Round 5
// 136.345 us; speedup vs baseline: 1.0254x; 1.0254x over previous
//
#include <hip/hip_runtime.h>

#define HW 16384

typedef __attribute__((ext_vector_type(8))) __bf16 bf16x8;
typedef __attribute__((ext_vector_type(16))) float floatx16;
typedef __attribute__((ext_vector_type(8))) unsigned short ushort8_t;

typedef const __attribute__((address_space(1))) unsigned int gu32;
typedef __attribute__((address_space(3))) unsigned int lu32;

__device__ __forceinline__ unsigned short f2bf(float f) {
    // round-to-nearest-even fp32 -> bf16
    unsigned int u = __builtin_bit_cast(unsigned int, f);
    unsigned int r = (u + 0x7FFFu + ((u >> 16) & 1u)) >> 16;
    return (unsigned short)r;
}

__device__ __forceinline__ void gload_lds16(const unsigned short* g, unsigned short* l) {
    __builtin_amdgcn_global_load_lds((gu32*)g, (lu32*)l, 16, 0, 0);
}

// Pre-convert W to bf16 in per-kt tiles [256 rows][64 k], XOR-swizzled so the main
// kernel can global_load_lds linearly and ds_read with the same involution.
// ushort index within tile: (row*64 + kl) ^ ((row&7)<<3); tile kt base = kt*16384.
__global__ void wconv_kernel(const float* __restrict__ w, unsigned short* __restrict__ wb) {
    int i = blockIdx.x * 256 + threadIdx.x;   // 65536 elements, i = row*256 + c
    int row = i >> 8, c = i & 255;
    int kt = c >> 6, kl = c & 63;
    int idx = (row * 64 + kl) ^ ((row & 7) << 3);
    wb[kt * 16384 + idx] = f2bf(w[i]);
}

// Block: 256 output channels x 256 pixels, K=256, ZERO in-loop barriers.
// Entire W (128 KB bf16) staged to LDS once; 8 waves partition pixels (32 px each),
// each wave computes all channels with mfma_32x32x16 (acc = 8 x f32x16).
// X: B-fragments from coalesced global dword loads (lane&31 = pixel, lane>>5 = 8-ch
// chunk -> 2x128B full-line segments/instr), prefetched one kt ahead; no syncthreads
// after the W stage, so loads stay in flight across the whole K loop.
// Lifting epilogue lane-local via 32x32 C/D map: col=lane&31, row=(reg&3)+8*(reg>>2)+4*(lane>>5).
__global__ __launch_bounds__(512, 2) void fused_gemm_lift(
        const float* __restrict__ x,
        const unsigned short* __restrict__ wb,
        const float* __restrict__ lp_v,
        const float* __restrict__ hp_v,
        const float* __restrict__ lp_h,
        const float* __restrict__ hp_h,
        float* __restrict__ out) {
    __shared__ alignas(16) unsigned short wbuf_s[4][16384];  // full W: 4 kt-tiles, 128 KB

    const int tid  = threadIdx.x;
    const int wv   = tid >> 6;
    const int lane = tid & 63;
    const int l31  = lane & 31;     // pixel within wave's 32-px tile / row within m-tile
    const int chunk = lane >> 5;    // 8-channel k-chunk select
    const int tile = blockIdx.x & 63;
    const int bb   = blockIdx.x >> 6;
    const int p0   = tile * 256;

    const float* xp = x + (size_t)bb * 256 * HW + p0 + wv * 32 + l31;  // lane's pixel column

    floatx16 acc[8];
    #pragma unroll
    for (int mt = 0; mt < 8; ++mt)
        #pragma unroll
        for (int e = 0; e < 16; ++e) acc[mt][e] = 0.f;

    float xf[2][32];

    // ---- prologue: X[kt=0] -> regs, full W -> LDS (the only barrier) ----
    #pragma unroll
    for (int jj = 0; jj < 32; ++jj) {
        int c = (jj >> 3) * 16 + chunk * 8 + (jj & 7);
        xf[0][jj] = xp[(size_t)c * HW];
    }
    #pragma unroll
    for (int p = 0; p < 16; ++p)
        gload_lds16(wb + (size_t)(p * 512 + tid) * 8, &wbuf_s[0][0] + (size_t)(p * 512 + tid) * 8);
    __syncthreads();

    #pragma unroll
    for (int kt = 0; kt < 4; ++kt) {
        const int cw = kt & 1;

        // prefetch X[kt+1] (fire-and-forget; lands under this kt's compute)
        if (kt < 3) {
            #pragma unroll
            for (int jj = 0; jj < 32; ++jj) {
                int c = (kt + 1) * 64 + (jj >> 3) * 16 + chunk * 8 + (jj & 7);
                xf[cw ^ 1][jj] = xp[(size_t)c * HW];
            }
        }

        // compute: 4 k16-steps x (pack B + 8 ds_read_b128 A + 8 MFMA)
        #pragma unroll
        for (int k16 = 0; k16 < 4; ++k16) {
            ushort8_t u;
            #pragma unroll
            for (int j = 0; j < 8; ++j) u[j] = f2bf(xf[cw][k16 * 8 + j]);
            const bf16x8 bq = __builtin_bit_cast(bf16x8, u);
            const int kl = k16 * 16 + chunk * 8;
            #pragma unroll
            for (int mt = 0; mt < 8; ++mt) {
                const int row = mt * 32 + l31;
                bf16x8 af = *reinterpret_cast<const bf16x8*>(
                    &wbuf_s[kt][(row * 64 + kl) ^ ((row & 7) << 3)]);
                acc[mt] = __builtin_amdgcn_mfma_f32_32x32x16_bf16(af, bq, acc[mt], 0, 0, 0);
            }
        }
    }

    // ---- fused lifting epilogue (lane-local) ----
    const int px = p0 + wv * 32 + l31;
    const int h  = px >> 7;
    const int w  = px & 127;
    float* outbase = out + (size_t)bb * 64 * 65536 + (size_t)(2 * h) * 256 + 2 * w;
    const int hi = lane >> 5;
    #pragma unroll
    for (int mt2 = 0; mt2 < 2; ++mt2)
        #pragma unroll
        for (int reg = 0; reg < 16; ++reg) {
            const int row = (reg & 3) + 8 * (reg >> 2) + 4 * hi;
            const int q = mt2 * 32 + row;
            const float2 lv = *reinterpret_cast<const float2*>(lp_v + 2 * q);
            const float2 hv = *reinterpret_cast<const float2*>(hp_v + 2 * q);
            const float2 lh = *reinterpret_cast<const float2*>(lp_h + 2 * q);
            const float2 hh = *reinterpret_cast<const float2*>(hp_h + 2 * q);
            const float a  = acc[mt2][reg];
            const float b2 = acc[mt2 + 2][reg];
            const float c2 = acc[mt2 + 4][reg];
            const float d2 = acc[mt2 + 6][reg];
            const float xl0 = lv.x * a + lv.y * b2;   // x_l even output row
            const float xl1 = hv.x * a + hv.y * b2;   // x_l odd output row
            const float xh0 = lv.x * c2 + lv.y * d2;  // x_h even
            const float xh1 = hv.x * c2 + hv.y * d2;  // x_h odd
            float2 r0 = make_float2(lh.x * xl0 + lh.y * xh0, hh.x * xl0 + hh.y * xh0);
            float2 r1 = make_float2(lh.x * xl1 + lh.y * xh1, hh.x * xl1 + hh.y * xh1);
            float* oq = outbase + (size_t)q * 65536;
            *reinterpret_cast<float2*>(oq)       = r0;
            *reinterpret_cast<float2*>(oq + 256) = r1;
        }
}

extern "C" void kernel_launch(void* const* d_in, const int* in_sizes, int n_in,
                              void* d_out, int out_size, void* d_ws, size_t ws_size,
                              hipStream_t stream) {
    const float* x   = (const float*)d_in[0];
    const float* w   = (const float*)d_in[1];
    const float* lpv = (const float*)d_in[2];
    const float* hpv = (const float*)d_in[3];
    const float* lph = (const float*)d_in[4];
    const float* hph = (const float*)d_in[5];
    float* outp = (float*)d_out;
    unsigned short* wbp = (unsigned short*)d_ws;   // 128 KB bf16 weights, pre-swizzled tiles

    wconv_kernel<<<dim3(256), dim3(256), 0, stream>>>(w, wbp);
    fused_gemm_lift<<<dim3(1024), dim3(512), 0, stream>>>(x, wbp, lpv, hpv, lph, hph, outp);
}